// Round 10
// baseline (376.221 us; speedup 1.0000x reference)
//
#include <hip/hip_runtime.h>
#include <hip/hip_bf16.h>

typedef unsigned short ushort_t;
typedef unsigned int uint_t;
typedef __attribute__((ext_vector_type(8))) short bf16x8;
typedef __attribute__((ext_vector_type(4))) float f32x4;

#define NNODE 2000
#define NB 8
#define LSEQ 12
#define HDIM 64
#define NEDGE 16000
#define NSEQ (NNODE * NB)            // 16000 sequences
#define OUT1_ELEMS (NNODE * NB * LSEQ * HDIM)   // 12,288,000
#define OUT1_BYTES (OUT1_ELEMS * 2)             // bf16 intermediate: 24,576,000
#define AGG_BYTES  (OUT1_ELEMS * 4)             // fp32: 49,152,000

__device__ __forceinline__ float bf1(ushort_t u) { return __uint_as_float(((uint_t)u) << 16); }
__device__ __forceinline__ ushort_t fbf(float f) {
    uint_t x = __float_as_uint(f);
    uint_t r = x + 0x7fffu + ((x >> 16) & 1u);   // RNE
    return (ushort_t)(r >> 16);
}
__device__ __forceinline__ uint_t pk2(float lo, float hi) {
    __hip_bfloat162 t = __float22bfloat162_rn(float2{lo, hi});
    return *(uint_t*)&t;   // low ushort = bf(lo)
}
__device__ __forceinline__ float sigm(float x) { return 1.f / (1.f + __expf(-x)); }
__device__ __forceinline__ float tanh_fast(float x) { return 2.f / (1.f + __expf(-2.f * x)) - 1.f; }

// ===========================================================================
// MFMA geometry (HW-verified R3): A[m=lane&15][k=quad*8+jj];
// B[k=ks*32+quad*8+jj][n=lane&15]; C row(M)=quad*4+reg, col(N)=lane&15.
// ===========================================================================

// ---------------------------------------------------------------------------
// GRU1: x_t is only 2-wide -> gi on VALU; gh via MFMA. out1 bf16 per step.
// ---------------------------------------------------------------------------
__global__ __launch_bounds__(512, 2) void gru1_kernel(
    const float* __restrict__ data, const float* __restrict__ Wih,
    const float* __restrict__ Whh, const float* __restrict__ bih,
    const float* __restrict__ bhh, ushort_t* __restrict__ out1,
    float* __restrict__ h1out)
{
    __shared__ ushort_t H[64][72] __attribute__((aligned(16)));  // 9216 B
    __shared__ float XD[64][26];                                 // 6656 B

    const int tid = threadIdx.x;
    const int wv = tid >> 6;
    const int mw = wv & 1, nw = wv >> 1;
    const int c = tid & 15;
    const int quad = (tid >> 4) & 3;
    const int j = nw * 16 + c;
    const int s0 = blockIdx.x * 64;

    *(uint4*)&H[tid & 63][(tid >> 6) * 8] = uint4{0, 0, 0, 0};
#pragma unroll
    for (int p = 0; p < 3; ++p) {
        const int flat = p * 512 + tid;     // 0..1535
        const int sl = flat / 24, q = flat - sl * 24;
        XD[sl][q] = data[(s0 + sl) * 24 + q];
    }

    bf16x8 Bh[3][2];
    float wi0[3], wi1[3], bi[3], bh[3];
#pragma unroll
    for (int g = 0; g < 3; ++g) {
        const int row = g * 64 + j;
        float2 wi = *(const float2*)(Wih + row * 2);
        wi0[g] = wi.x; wi1[g] = wi.y;
        bi[g] = bih[row]; bh[g] = bhh[row];
#pragma unroll
        for (int ks = 0; ks < 2; ++ks) {
            const float* wp = Whh + (row << 6) + ks * 32 + quad * 8;
            float4 wa = *(const float4*)wp;
            float4 wb = *(const float4*)(wp + 4);
            ushort_t tmp[8];
            tmp[0] = fbf(wa.x); tmp[1] = fbf(wa.y); tmp[2] = fbf(wa.z); tmp[3] = fbf(wa.w);
            tmp[4] = fbf(wb.x); tmp[5] = fbf(wb.y); tmp[6] = fbf(wb.z); tmp[7] = fbf(wb.w);
            Bh[g][ks] = *(bf16x8*)tmp;
        }
    }

    float hold[2][4];
#pragma unroll
    for (int mt = 0; mt < 2; ++mt)
#pragma unroll
        for (int rg = 0; rg < 4; ++rg) hold[mt][rg] = 0.f;

    for (int t = 0; t < LSEQ; ++t) {
        __syncthreads();   // A: H (+XD at t=0) visible
#pragma unroll
        for (int mt = 0; mt < 2; ++mt) {
            bf16x8 a0 = *(const bf16x8*)&H[mw * 32 + mt * 16 + c][quad * 8];
            bf16x8 a1 = *(const bf16x8*)&H[mw * 32 + mt * 16 + c][32 + quad * 8];
            f32x4 gh[3];
#pragma unroll
            for (int g = 0; g < 3; ++g) {
                f32x4 acc = {0.f, 0.f, 0.f, 0.f};
                acc = __builtin_amdgcn_mfma_f32_16x16x32_bf16(a0, Bh[g][0], acc, 0, 0, 0);
                acc = __builtin_amdgcn_mfma_f32_16x16x32_bf16(a1, Bh[g][1], acc, 0, 0, 0);
                gh[g] = acc;
            }
            ushort_t hnb[4];
#pragma unroll
            for (int rg = 0; rg < 4; ++rg) {
                const int sloc = mw * 32 + mt * 16 + quad * 4 + rg;
                float2 xp = *(const float2*)&XD[sloc][2 * t];
                float gr = bh[0] + gh[0][rg];
                float gz = bh[1] + gh[1][rg];
                float gn = bh[2] + gh[2][rg];
                float ir = bi[0] + wi0[0] * xp.x + wi1[0] * xp.y;
                float iz = bi[1] + wi0[1] * xp.x + wi1[1] * xp.y;
                float in = bi[2] + wi0[2] * xp.x + wi1[2] * xp.y;
                float r = sigm(ir + gr);
                float z = sigm(iz + gz);
                float n = tanh_fast(in + r * gn);
                float hv = (1.f - z) * n + z * hold[mt][rg];
                hold[mt][rg] = hv;
                hnb[rg] = fbf(hv);
            }
            __syncthreads();   // B
#pragma unroll
            for (int rg = 0; rg < 4; ++rg) {
                const int sloc = mw * 32 + mt * 16 + quad * 4 + rg;
                H[sloc][j] = hnb[rg];
                out1[(s0 + sloc) * (LSEQ * HDIM) + t * HDIM + j] = hnb[rg];
            }
        }
    }
#pragma unroll
    for (int mt = 0; mt < 2; ++mt)
#pragma unroll
        for (int rg = 0; rg < 4; ++rg) {
            const int sloc = mw * 32 + mt * 16 + quad * 4 + rg;
            h1out[(s0 + sloc) * HDIM + j] = hold[mt][rg];
        }
}

// ---------------------------------------------------------------------------
// CSR helpers: degree histogram -> single-block scan -> scatter src+edge ids.
// ---------------------------------------------------------------------------
__global__ __launch_bounds__(256) void count_kernel(const int* __restrict__ edges,
                                                    int* __restrict__ degree)
{
    const int e = blockIdx.x * 256 + threadIdx.x;
    if (e < NEDGE) atomicAdd(&degree[edges[NEDGE + e]], 1);
}

__global__ __launch_bounds__(256) void scan_kernel(const int* __restrict__ degree,
                                                   int* __restrict__ rowstart)
{
    __shared__ int part[256];
    const int t = threadIdx.x;
    const int base = t * 8;
    int s = 0;
#pragma unroll
    for (int q = 0; q < 8; ++q) { const int idx = base + q; if (idx < NNODE) s += degree[idx]; }
    part[t] = s;
    __syncthreads();
    if (t == 0) {
        int run = 0;
        for (int u = 0; u < 256; ++u) { const int v = part[u]; part[u] = run; run += v; }
    }
    __syncthreads();
    int run = part[t];
#pragma unroll
    for (int q = 0; q < 8; ++q) {
        const int idx = base + q;
        if (idx < NNODE) { rowstart[idx] = run; run += degree[idx]; }
    }
}

__global__ __launch_bounds__(256) void scatter_kernel(const int* __restrict__ edges,
                                                      const int* __restrict__ rowstart,
                                                      int* __restrict__ cursor,
                                                      int* __restrict__ srcids,
                                                      int* __restrict__ eids)
{
    const int e = blockIdx.x * 256 + threadIdx.x;
    if (e < NEDGE) {
        const int d = edges[NEDGE + e];
        const int pos = atomicAdd(&cursor[d], 1);
        srcids[rowstart[d] + pos] = edges[e];   // src node
        eids[rowstart[d] + pos] = e;            // edge id (alpha index)
    }
}

// ---------------------------------------------------------------------------
// Per-edge MLP hoisted: alphas[2e] = (a0,a1), all 18000 edges incl. self.
// ---------------------------------------------------------------------------
__global__ __launch_bounds__(256) void alpha_kernel(
    const float* __restrict__ features, const int* __restrict__ edges,
    const float* __restrict__ W1, const float* __restrict__ b1,
    const float* __restrict__ W2, const float* __restrict__ b2,
    float* __restrict__ alphas)
{
    __shared__ float m1[4][16];
    const int tid = threadIdx.x;
    const int w = tid >> 6, lane = tid & 63;
    const int e = blockIdx.x * 4 + w;           // grid sized exactly 18000/4
    int i, j;
    if (e < NEDGE) { j = edges[e]; i = edges[NEDGE + e]; }
    else { i = j = e - NEDGE; }

    const int o = lane >> 2, q = lane & 3;      // 16 outputs x 4 partials
    const float* fsrc = (q < 2) ? (features + i * 64 + q * 32)
                                : (features + j * 64 + (q - 2) * 32);
    const float* wsrc = W1 + o * 128 + q * 32;
    float acc = 0.f;
#pragma unroll
    for (int k = 0; k < 32; ++k) acc += fsrc[k] * wsrc[k];
    acc += __shfl_xor(acc, 1);
    acc += __shfl_xor(acc, 2);
    if (q == 0) m1[w][o] = sigm(acc + b1[o]);
    __syncthreads();
    if (lane < 32) {
        const int o2 = lane >> 4, k = lane & 15;
        float p = m1[w][k] * W2[o2 * 16 + k];
        p += __shfl_xor(p, 1);
        p += __shfl_xor(p, 2);
        p += __shfl_xor(p, 4);
        p += __shfl_xor(p, 8);
        if (k == 0) alphas[e * 2 + o2] = sigm(p + b2[o2]);
    }
}

// ---------------------------------------------------------------------------
// MetaGAT (CSR, MFMA, K-split, REGISTER-DIRECT): 2 blocks per dst (M-halves,
// 48 rows). NO LDS, NO barriers: every wave independently streams its A-frags
// (16B contiguous chunks of out1) and msg elements (u16) straight from
// global (L2-hot) into registers, ping-pong one edge ahead (literal-indexed
// A/B buffers). K-split: S@w = [a0*PA + a1*PB + PC] + Sj@w_bot with the Si
// projections computed once (18 preamble MFMAs). w_bot pinned in VGPRs.
// ---------------------------------------------------------------------------
__global__ __launch_bounds__(256) void gat_csr_kernel(
    const ushort_t* __restrict__ out1,
    const int* __restrict__ degree, const int* __restrict__ rowstart,
    const int* __restrict__ srcids, const int* __restrict__ eids,
    const float* __restrict__ alphas,
    const float* __restrict__ W3, const float* __restrict__ b3,
    float* __restrict__ agg)
{
    const int tid = threadIdx.x;
    const int i = blockIdx.x >> 1;
    const int mh = blockIdx.x & 1;        // M-half: rows 48*mh .. 48*mh+47
    const int deg = degree[i];
    const int rs = rowstart[i];

    const int wv = tid >> 6;              // N-strip
    const int r = tid & 15;
    const int quad = (tid >> 4) & 3;
    const int n = wv * 16 + r;

    // lane-private element offsets within a node's 96x64 state block
    int aoff[3];                          // A-frag base (row mt*16+r, col quad*8)
#pragma unroll
    for (int mt = 0; mt < 3; ++mt) {
        const int row = 48 * mh + mt * 16 + r;      // = l*8 + b
        const int b = row & 7, l = row >> 3;
        aoff[mt] = (b * 12 + l) * 64 + quad * 8;
    }
    int moff[12];                         // msg element (row mt*16+quad*4+g2, col n)
#pragma unroll
    for (int mt = 0; mt < 3; ++mt)
#pragma unroll
        for (int g2 = 0; g2 < 4; ++g2) {
            const int row = 48 * mh + mt * 16 + quad * 4 + g2;
            const int b = row & 7, l = row >> 3;
            moff[mt * 4 + g2] = (b * 12 + l) * 64 + n;
        }

    const ushort_t* pi = out1 + i * (NB * LSEQ * HDIM);

    // ---- pin w_bot columns (k = 64 + ks*32 + quad*8 + jj) ----
    float wba[16], wbb[16], wbc[16];
#pragma unroll
    for (int ks = 0; ks < 2; ++ks)
#pragma unroll
        for (int jj = 0; jj < 8; ++jj) {
            const int m = (64 + ks * 32 + quad * 8 + jj) * 64 + n;
            float2 w2 = ((const float2*)W3)[m];
            wba[ks * 8 + jj] = w2.x; wbb[ks * 8 + jj] = w2.y; wbc[ks * 8 + jj] = b3[m];
        }

    // ---- Si fragments direct from global ----
    bf16x8 si0[3], si1[3];
#pragma unroll
    for (int mt = 0; mt < 3; ++mt) {
        si0[mt] = *(const bf16x8*)(pi + aoff[mt]);
        si1[mt] = *(const bf16x8*)(pi + aoff[mt] + 32);
    }
    ushort_t mei[12];
#pragma unroll
    for (int q = 0; q < 12; ++q) mei[q] = pi[moff[q]];

    // ---- W-top frags + preamble: PA/PB/PC ----
    f32x4 PA[3], PB[3], PC[3];
    {
        bf16x8 WtA[2], WtB[2], WtC[2];
#pragma unroll
        for (int ks = 0; ks < 2; ++ks) {
            ushort_t ta[8], tb[8], tc[8];
#pragma unroll
            for (int jj = 0; jj < 8; ++jj) {
                const int m = (ks * 32 + quad * 8 + jj) * 64 + n;
                float2 w2 = ((const float2*)W3)[m];
                ta[jj] = fbf(w2.x); tb[jj] = fbf(w2.y); tc[jj] = fbf(b3[m]);
            }
            WtA[ks] = *(bf16x8*)ta; WtB[ks] = *(bf16x8*)tb; WtC[ks] = *(bf16x8*)tc;
        }
#pragma unroll
        for (int mt = 0; mt < 3; ++mt) {
            f32x4 pa = {0.f, 0.f, 0.f, 0.f};
            f32x4 pb = {0.f, 0.f, 0.f, 0.f};
            f32x4 pc = {0.f, 0.f, 0.f, 0.f};
            pa = __builtin_amdgcn_mfma_f32_16x16x32_bf16(si0[mt], WtA[0], pa, 0, 0, 0);
            pa = __builtin_amdgcn_mfma_f32_16x16x32_bf16(si1[mt], WtA[1], pa, 0, 0, 0);
            pb = __builtin_amdgcn_mfma_f32_16x16x32_bf16(si0[mt], WtB[0], pb, 0, 0, 0);
            pb = __builtin_amdgcn_mfma_f32_16x16x32_bf16(si1[mt], WtB[1], pb, 0, 0, 0);
            pc = __builtin_amdgcn_mfma_f32_16x16x32_bf16(si0[mt], WtC[0], pc, 0, 0, 0);
            pc = __builtin_amdgcn_mfma_f32_16x16x32_bf16(si1[mt], WtC[1], pc, 0, 0, 0);
            PA[mt] = pa; PB[mt] = pb; PC[mt] = pc;
        }
    }

    float accN[3][4];
#pragma unroll
    for (int mt = 0; mt < 3; ++mt)
#pragma unroll
        for (int g2 = 0; g2 < 4; ++g2) accN[mt][g2] = 0.f;

    // process one edge entirely from registers
    auto process = [&](const bf16x8* f0, const bf16x8* f1, const ushort_t* me,
                       float2 a01) {
        bf16x8 bfrag[2];
#pragma unroll
        for (int ks = 0; ks < 2; ++ks) {
            uint_t tmp[4];
#pragma unroll
            for (int q2 = 0; q2 < 4; ++q2) {
                const int q = ks * 8 + q2 * 2;
                float v0 = fmaf(a01.y, wbb[q], fmaf(a01.x, wba[q], wbc[q]));
                float v1 = fmaf(a01.y, wbb[q + 1], fmaf(a01.x, wba[q + 1], wbc[q + 1]));
                tmp[q2] = pk2(v0, v1);
            }
            bfrag[ks] = *(bf16x8*)tmp;
        }
#pragma unroll
        for (int mt = 0; mt < 3; ++mt) {
            f32x4 acc = {0.f, 0.f, 0.f, 0.f};
            acc = __builtin_amdgcn_mfma_f32_16x16x32_bf16(f0[mt], bfrag[0], acc, 0, 0, 0);
            acc = __builtin_amdgcn_mfma_f32_16x16x32_bf16(f1[mt], bfrag[1], acc, 0, 0, 0);
            float v[4];
#pragma unroll
            for (int g2 = 0; g2 < 4; ++g2) {
                float x = acc[g2] + fmaf(a01.x, PA[mt][g2],
                              fmaf(a01.y, PB[mt][g2], PC[mt][g2]));
                v[g2] = x > 0.f ? x : 0.01f * x;   // leaky_relu
            }
            float mx = fmaxf(fmaxf(v[0], v[1]), fmaxf(v[2], v[3]));
            mx = fmaxf(mx, __shfl_xor(mx, 16));
            float s = 0.f;
#pragma unroll
            for (int g2 = 0; g2 < 4; ++g2) { v[g2] = __expf(v[g2] - mx); s += v[g2]; }
            s += __shfl_xor(s, 16);
            const float inv = 1.f / s;
#pragma unroll
            for (int g2 = 0; g2 < 4; ++g2)
                accN[mt][g2] += v[g2] * inv * bf1(me[mt * 4 + g2]);
        }
    };

    // ---- ping-pong buffers ----
    bf16x8 fA0[3], fA1[3], fB0[3], fB1[3];
    ushort_t meA[12], meB[12];

    // preload edge 0 -> B (issued before self-loop compute to hide latency)
    if (deg > 0) {
        const ushort_t* pj = out1 + srcids[rs] * (NB * LSEQ * HDIM);
#pragma unroll
        for (int mt = 0; mt < 3; ++mt) {
            fB0[mt] = *(const bf16x8*)(pj + aoff[mt]);
            fB1[mt] = *(const bf16x8*)(pj + aoff[mt] + 32);
        }
#pragma unroll
        for (int q = 0; q < 12; ++q) meB[q] = pj[moff[q]];
    }

    // self loop (Si frags, Si msg)
    process(si0, si1, mei, *(const float2*)(alphas + (NEDGE + i) * 2));

    for (int base = 0; base < deg; base += 2) {
        if (base + 1 < deg) {
            const ushort_t* pj = out1 + srcids[rs + base + 1] * (NB * LSEQ * HDIM);
#pragma unroll
            for (int mt = 0; mt < 3; ++mt) {
                fA0[mt] = *(const bf16x8*)(pj + aoff[mt]);
                fA1[mt] = *(const bf16x8*)(pj + aoff[mt] + 32);
            }
#pragma unroll
            for (int q = 0; q < 12; ++q) meA[q] = pj[moff[q]];
        }
        process(fB0, fB1, meB, *(const float2*)(alphas + eids[rs + base] * 2));
        if (base + 2 < deg) {
            const ushort_t* pj = out1 + srcids[rs + base + 2] * (NB * LSEQ * HDIM);
#pragma unroll
            for (int mt = 0; mt < 3; ++mt) {
                fB0[mt] = *(const bf16x8*)(pj + aoff[mt]);
                fB1[mt] = *(const bf16x8*)(pj + aoff[mt] + 32);
            }
#pragma unroll
            for (int q = 0; q < 12; ++q) meB[q] = pj[moff[q]];
        }
        if (base + 1 < deg)
            process(fA0, fA1, meA, *(const float2*)(alphas + eids[rs + base + 1] * 2));
    }

    // single non-atomic store of this half-node's aggregate
#pragma unroll
    for (int mt = 0; mt < 3; ++mt)
#pragma unroll
        for (int g2 = 0; g2 < 4; ++g2) {
            const int gr = 48 * mh + mt * 16 + quad * 4 + g2;  // = l*8 + b
            const int b = gr & 7, l = gr >> 3;
            agg[(i * 96 + b * 12 + l) * 64 + n] = accN[mt][g2];
        }
}

// ---------------------------------------------------------------------------
// GRU2: gi AND gh via MFMA; x_t = relu(agg) staged bf16, next-step global
// load software-pipelined under the MFMAs.
// ---------------------------------------------------------------------------
__global__ __launch_bounds__(512, 2) void gru2_kernel(
    const float* __restrict__ agg, const float* __restrict__ Wih,
    const float* __restrict__ Whh, const float* __restrict__ bih,
    const float* __restrict__ bhh, float* __restrict__ h2out)
{
    __shared__ ushort_t H[64][72] __attribute__((aligned(16)));  // 9216 B
    __shared__ ushort_t X[64][72] __attribute__((aligned(16)));  // 9216 B

    const int tid = threadIdx.x;
    const int wv = tid >> 6;
    const int mw = wv & 1, nw = wv >> 1;
    const int c = tid & 15;
    const int quad = (tid >> 4) & 3;
    const int j = nw * 16 + c;
    const int s0 = blockIdx.x * 64;
    const int sl = tid >> 3, k0 = (tid & 7) * 8;

    *(uint4*)&H[tid & 63][(tid >> 6) * 8] = uint4{0, 0, 0, 0};

    bf16x8 Bh[3][2], Bi[3][2];
    float bi[3], bh[3];
#pragma unroll
    for (int g = 0; g < 3; ++g) {
        const int row = g * 64 + j;
        bi[g] = bih[row]; bh[g] = bhh[row];
#pragma unroll
        for (int ks = 0; ks < 2; ++ks) {
            const float* wp = Whh + (row << 6) + ks * 32 + quad * 8;
            float4 wa = *(const float4*)wp;
            float4 wb = *(const float4*)(wp + 4);
            ushort_t tmp[8];
            tmp[0] = fbf(wa.x); tmp[1] = fbf(wa.y); tmp[2] = fbf(wa.z); tmp[3] = fbf(wa.w);
            tmp[4] = fbf(wb.x); tmp[5] = fbf(wb.y); tmp[6] = fbf(wb.z); tmp[7] = fbf(wb.w);
            Bh[g][ks] = *(bf16x8*)tmp;
            const float* wp2 = Wih + (row << 6) + ks * 32 + quad * 8;
            float4 va = *(const float4*)wp2;
            float4 vb = *(const float4*)(wp2 + 4);
            tmp[0] = fbf(va.x); tmp[1] = fbf(va.y); tmp[2] = fbf(va.z); tmp[3] = fbf(va.w);
            tmp[4] = fbf(vb.x); tmp[5] = fbf(vb.y); tmp[6] = fbf(vb.z); tmp[7] = fbf(vb.w);
            Bi[g][ks] = *(bf16x8*)tmp;
        }
    }

    float hold[2][4];
#pragma unroll
    for (int mt = 0; mt < 2; ++mt)
#pragma unroll
        for (int rg = 0; rg < 4; ++rg) hold[mt][rg] = 0.f;

    float xr[8];
    {
        const float* gp = agg + (s0 + sl) * (LSEQ * HDIM) + k0;
        *(float4*)&xr[0] = *(const float4*)gp;
        *(float4*)&xr[4] = *(const float4*)(gp + 4);
    }

    for (int t = 0; t < LSEQ; ++t) {
        {
            ushort_t xs[8];
#pragma unroll
            for (int q = 0; q < 8; ++q) xs[q] = fbf(xr[q] > 0.f ? xr[q] : 0.f);
            *(uint4*)&X[sl][k0] = *(uint4*)xs;
        }
        __syncthreads();   // A: X_t + H_t visible
        if (t < LSEQ - 1) {
            const float* gp = agg + (s0 + sl) * (LSEQ * HDIM) + (t + 1) * HDIM + k0;
            *(float4*)&xr[0] = *(const float4*)gp;
            *(float4*)&xr[4] = *(const float4*)(gp + 4);
        }
#pragma unroll
        for (int mt = 0; mt < 2; ++mt) {
            const int mrow = mw * 32 + mt * 16 + c;
            bf16x8 ah0 = *(const bf16x8*)&H[mrow][quad * 8];
            bf16x8 ah1 = *(const bf16x8*)&H[mrow][32 + quad * 8];
            bf16x8 ax0 = *(const bf16x8*)&X[mrow][quad * 8];
            bf16x8 ax1 = *(const bf16x8*)&X[mrow][32 + quad * 8];
            f32x4 gh[3], gi[3];
#pragma unroll
            for (int g = 0; g < 3; ++g) {
                f32x4 acc = {0.f, 0.f, 0.f, 0.f};
                acc = __builtin_amdgcn_mfma_f32_16x16x32_bf16(ah0, Bh[g][0], acc, 0, 0, 0);
                acc = __builtin_amdgcn_mfma_f32_16x16x32_bf16(ah1, Bh[g][1], acc, 0, 0, 0);
                gh[g] = acc;
                f32x4 acc2 = {0.f, 0.f, 0.f, 0.f};
                acc2 = __builtin_amdgcn_mfma_f32_16x16x32_bf16(ax0, Bi[g][0], acc2, 0, 0, 0);
                acc2 = __builtin_amdgcn_mfma_f32_16x16x32_bf16(ax1, Bi[g][1], acc2, 0, 0, 0);
                gi[g] = acc2;
            }
            ushort_t hnb[4];
#pragma unroll
            for (int rg = 0; rg < 4; ++rg) {
                float r = sigm(bi[0] + gi[0][rg] + bh[0] + gh[0][rg]);
                float z = sigm(bi[1] + gi[1][rg] + bh[1] + gh[1][rg]);
                float n = tanh_fast(bi[2] + gi[2][rg] + r * (bh[2] + gh[2][rg]));
                float hv = (1.f - z) * n + z * hold[mt][rg];
                hold[mt][rg] = hv;
                hnb[rg] = fbf(hv);
            }
            __syncthreads();   // B
#pragma unroll
            for (int rg = 0; rg < 4; ++rg) {
                const int sloc = mw * 32 + mt * 16 + quad * 4 + rg;
                H[sloc][j] = hnb[rg];
            }
        }
    }
#pragma unroll
    for (int mt = 0; mt < 2; ++mt)
#pragma unroll
        for (int rg = 0; rg < 4; ++rg) {
            const int sloc = mw * 32 + mt * 16 + quad * 4 + rg;
            h2out[(s0 + sloc) * HDIM + j] = hold[mt][rg];
        }
}

extern "C" void kernel_launch(void* const* d_in, const int* in_sizes, int n_in,
                              void* d_out, int out_size, void* d_ws, size_t ws_size,
                              hipStream_t stream)
{
    const float* data     = (const float*)d_in[0];
    const float* features = (const float*)d_in[1];
    const int*   edges    = (const int*)d_in[2];
    const float* Wih1     = (const float*)d_in[3];
    const float* Whh1     = (const float*)d_in[4];
    const float* bih1     = (const float*)d_in[5];
    const float* bhh1     = (const float*)d_in[6];
    const float* W1       = (const float*)d_in[7];
    const float* b1       = (const float*)d_in[8];
    const float* W2       = (const float*)d_in[9];
    const float* b2       = (const float*)d_in[10];
    const float* W3       = (const float*)d_in[11];
    const float* b3       = (const float*)d_in[12];
    const float* Wih2     = (const float*)d_in[13];
    const float* Whh2     = (const float*)d_in[14];
    const float* bih2     = (const float*)d_in[15];
    const float* bhh2     = (const float*)d_in[16];

    float*    out  = (float*)d_out;
    char*     ws   = (char*)d_ws;
    ushort_t* out1 = (ushort_t*)ws;                    // bf16 intermediate
    float*    agg  = (float*)(ws + OUT1_BYTES);        // fp32 GAT output
    int*      meta = (int*)(ws + OUT1_BYTES + AGG_BYTES);
    int*   degree   = meta;                       // [2000]
    int*   cursor   = meta + NNODE;               // [2000]
    int*   rowstart = meta + 2 * NNODE;           // [2000]
    int*   srcids   = meta + 3 * NNODE;           // [16000]
    int*   eids     = meta + 3 * NNODE + NEDGE;   // [16000]
    float* alphas   = (float*)(meta + 3 * NNODE + 2 * NEDGE);  // [36000]

    hipMemsetAsync(meta, 0, 2 * NNODE * sizeof(int), stream);   // degree+cursor

    count_kernel<<<(NEDGE + 255) / 256, 256, 0, stream>>>(edges, degree);
    scan_kernel<<<1, 256, 0, stream>>>(degree, rowstart);
    scatter_kernel<<<(NEDGE + 255) / 256, 256, 0, stream>>>(edges, rowstart, cursor,
                                                            srcids, eids);
    alpha_kernel<<<(NEDGE + NNODE) / 4, 256, 0, stream>>>(features, edges,
                                                          W1, b1, W2, b2, alphas);

    gru1_kernel<<<NSEQ / 64, 512, 0, stream>>>(data, Wih1, Whh1, bih1, bhh1, out1, out);
    gat_csr_kernel<<<2 * NNODE, 256, 0, stream>>>(out1, degree, rowstart, srcids, eids,
                                                  alphas, W3, b3, agg);
    gru2_kernel<<<NSEQ / 64, 512, 0, stream>>>(agg, Wih2, Whh2, bih2, bhh2,
                                               out + NNODE * NB * HDIM);
}

// Round 11
// 338.836 us; speedup vs baseline: 1.1103x; 1.1103x over previous
//
#include <hip/hip_runtime.h>
#include <hip/hip_bf16.h>

typedef unsigned short ushort_t;
typedef unsigned int uint_t;
typedef __attribute__((ext_vector_type(8))) short bf16x8;
typedef __attribute__((ext_vector_type(4))) float f32x4;

#define NNODE 2000
#define NB 8
#define LSEQ 12
#define HDIM 64
#define NEDGE 16000
#define NSEQ (NNODE * NB)            // 16000 sequences
#define OUT1_ELEMS (NNODE * NB * LSEQ * HDIM)   // 12,288,000
#define OUT1_BYTES (OUT1_ELEMS * 2)             // bf16 intermediate: 24,576,000
#define AGG_BYTES  (OUT1_ELEMS * 4)             // fp32: 49,152,000

__device__ __forceinline__ float bf1(ushort_t u) { return __uint_as_float(((uint_t)u) << 16); }
__device__ __forceinline__ ushort_t fbf(float f) {
    uint_t x = __float_as_uint(f);
    uint_t r = x + 0x7fffu + ((x >> 16) & 1u);   // RNE
    return (ushort_t)(r >> 16);
}
__device__ __forceinline__ uint_t pk2(float lo, float hi) {
    __hip_bfloat162 t = __float22bfloat162_rn(float2{lo, hi});
    return *(uint_t*)&t;   // low ushort = bf(lo)
}
__device__ __forceinline__ float sigm(float x) { return 1.f / (1.f + __expf(-x)); }
__device__ __forceinline__ float tanh_fast(float x) { return 2.f / (1.f + __expf(-2.f * x)) - 1.f; }

// ===========================================================================
// MFMA geometry (HW-verified R3): A[m=lane&15][k=quad*8+jj];
// B[k=ks*32+quad*8+jj][n=lane&15]; C row(M)=quad*4+reg, col(N)=lane&15.
// GRU blocks now 32 seqs / 4 waves (wave = one 16-col N-strip, all 3 gates)
// so 500 blocks ~ 2 blocks/CU hide each other's barrier stalls.
// ===========================================================================

// ---------------------------------------------------------------------------
// GRU1: x_t is only 2-wide -> gi on VALU; gh via MFMA. out1 bf16 per step.
// ---------------------------------------------------------------------------
__global__ __launch_bounds__(256) void gru1_kernel(
    const float* __restrict__ data, const float* __restrict__ Wih,
    const float* __restrict__ Whh, const float* __restrict__ bih,
    const float* __restrict__ bhh, ushort_t* __restrict__ out1,
    float* __restrict__ h1out)
{
    __shared__ ushort_t H[32][72] __attribute__((aligned(16)));  // 4608 B
    __shared__ float XD[32][26];                                 // 3328 B

    const int tid = threadIdx.x;
    const int nw = tid >> 6;             // N-strip 0..3
    const int c = tid & 15;
    const int quad = (tid >> 4) & 3;
    const int j = nw * 16 + c;
    const int s0 = blockIdx.x * 32;

    *(uint4*)&H[tid & 31][(tid >> 5) * 8] = uint4{0, 0, 0, 0};
#pragma unroll
    for (int p = 0; p < 3; ++p) {
        const int flat = p * 256 + tid;     // 0..767
        const int sl = flat / 24, q = flat - sl * 24;
        XD[sl][q] = data[(s0 + sl) * 24 + q];
    }

    bf16x8 Bh[3][2];
    float wi0[3], wi1[3], bi[3], bh[3];
#pragma unroll
    for (int g = 0; g < 3; ++g) {
        const int row = g * 64 + j;
        float2 wi = *(const float2*)(Wih + row * 2);
        wi0[g] = wi.x; wi1[g] = wi.y;
        bi[g] = bih[row]; bh[g] = bhh[row];
#pragma unroll
        for (int ks = 0; ks < 2; ++ks) {
            const float* wp = Whh + (row << 6) + ks * 32 + quad * 8;
            float4 wa = *(const float4*)wp;
            float4 wb = *(const float4*)(wp + 4);
            ushort_t tmp[8];
            tmp[0] = fbf(wa.x); tmp[1] = fbf(wa.y); tmp[2] = fbf(wa.z); tmp[3] = fbf(wa.w);
            tmp[4] = fbf(wb.x); tmp[5] = fbf(wb.y); tmp[6] = fbf(wb.z); tmp[7] = fbf(wb.w);
            Bh[g][ks] = *(bf16x8*)tmp;
        }
    }

    float hold[2][4];
#pragma unroll
    for (int mt = 0; mt < 2; ++mt)
#pragma unroll
        for (int rg = 0; rg < 4; ++rg) hold[mt][rg] = 0.f;

    for (int t = 0; t < LSEQ; ++t) {
        __syncthreads();   // A: H (+XD at t=0) visible
        bf16x8 a0[2], a1[2];
#pragma unroll
        for (int mt = 0; mt < 2; ++mt) {
            a0[mt] = *(const bf16x8*)&H[mt * 16 + c][quad * 8];
            a1[mt] = *(const bf16x8*)&H[mt * 16 + c][32 + quad * 8];
        }
        ushort_t hnb[2][4];
#pragma unroll
        for (int mt = 0; mt < 2; ++mt) {
            f32x4 gh[3];
#pragma unroll
            for (int g = 0; g < 3; ++g) {
                f32x4 acc = {0.f, 0.f, 0.f, 0.f};
                acc = __builtin_amdgcn_mfma_f32_16x16x32_bf16(a0[mt], Bh[g][0], acc, 0, 0, 0);
                acc = __builtin_amdgcn_mfma_f32_16x16x32_bf16(a1[mt], Bh[g][1], acc, 0, 0, 0);
                gh[g] = acc;
            }
#pragma unroll
            for (int rg = 0; rg < 4; ++rg) {
                const int sloc = mt * 16 + quad * 4 + rg;
                float2 xp = *(const float2*)&XD[sloc][2 * t];
                float gr = bh[0] + gh[0][rg];
                float gz = bh[1] + gh[1][rg];
                float gn = bh[2] + gh[2][rg];
                float ir = bi[0] + wi0[0] * xp.x + wi1[0] * xp.y;
                float iz = bi[1] + wi0[1] * xp.x + wi1[1] * xp.y;
                float in = bi[2] + wi0[2] * xp.x + wi1[2] * xp.y;
                float r = sigm(ir + gr);
                float z = sigm(iz + gz);
                float n = tanh_fast(in + r * gn);
                float hv = (1.f - z) * n + z * hold[mt][rg];
                hold[mt][rg] = hv;
                hnb[mt][rg] = fbf(hv);
            }
        }
        __syncthreads();   // B: all A-frag reads done
#pragma unroll
        for (int mt = 0; mt < 2; ++mt)
#pragma unroll
            for (int rg = 0; rg < 4; ++rg) {
                const int sloc = mt * 16 + quad * 4 + rg;
                H[sloc][j] = hnb[mt][rg];
                out1[(s0 + sloc) * (LSEQ * HDIM) + t * HDIM + j] = hnb[mt][rg];
            }
    }
#pragma unroll
    for (int mt = 0; mt < 2; ++mt)
#pragma unroll
        for (int rg = 0; rg < 4; ++rg) {
            const int sloc = mt * 16 + quad * 4 + rg;
            h1out[(s0 + sloc) * HDIM + j] = hold[mt][rg];
        }
}

// ---------------------------------------------------------------------------
// CSR helpers: degree histogram -> single-block scan -> scatter src+edge ids.
// ---------------------------------------------------------------------------
__global__ __launch_bounds__(256) void count_kernel(const int* __restrict__ edges,
                                                    int* __restrict__ degree)
{
    const int e = blockIdx.x * 256 + threadIdx.x;
    if (e < NEDGE) atomicAdd(&degree[edges[NEDGE + e]], 1);
}

__global__ __launch_bounds__(256) void scan_kernel(const int* __restrict__ degree,
                                                   int* __restrict__ rowstart)
{
    __shared__ int part[256];
    const int t = threadIdx.x;
    const int base = t * 8;
    int s = 0;
#pragma unroll
    for (int q = 0; q < 8; ++q) { const int idx = base + q; if (idx < NNODE) s += degree[idx]; }
    part[t] = s;
    __syncthreads();
    if (t == 0) {
        int run = 0;
        for (int u = 0; u < 256; ++u) { const int v = part[u]; part[u] = run; run += v; }
    }
    __syncthreads();
    int run = part[t];
#pragma unroll
    for (int q = 0; q < 8; ++q) {
        const int idx = base + q;
        if (idx < NNODE) { rowstart[idx] = run; run += degree[idx]; }
    }
}

__global__ __launch_bounds__(256) void scatter_kernel(const int* __restrict__ edges,
                                                      const int* __restrict__ rowstart,
                                                      int* __restrict__ cursor,
                                                      int* __restrict__ srcids,
                                                      int* __restrict__ eids)
{
    const int e = blockIdx.x * 256 + threadIdx.x;
    if (e < NEDGE) {
        const int d = edges[NEDGE + e];
        const int pos = atomicAdd(&cursor[d], 1);
        srcids[rowstart[d] + pos] = edges[e];   // src node
        eids[rowstart[d] + pos] = e;            // edge id (alpha index)
    }
}

// ---------------------------------------------------------------------------
// Per-edge MLP hoisted: alphas[2e] = (a0,a1), all 18000 edges incl. self.
// ---------------------------------------------------------------------------
__global__ __launch_bounds__(256) void alpha_kernel(
    const float* __restrict__ features, const int* __restrict__ edges,
    const float* __restrict__ W1, const float* __restrict__ b1,
    const float* __restrict__ W2, const float* __restrict__ b2,
    float* __restrict__ alphas)
{
    __shared__ float m1[4][16];
    const int tid = threadIdx.x;
    const int w = tid >> 6, lane = tid & 63;
    const int e = blockIdx.x * 4 + w;           // grid sized exactly 18000/4
    int i, j;
    if (e < NEDGE) { j = edges[e]; i = edges[NEDGE + e]; }
    else { i = j = e - NEDGE; }

    const int o = lane >> 2, q = lane & 3;      // 16 outputs x 4 partials
    const float* fsrc = (q < 2) ? (features + i * 64 + q * 32)
                                : (features + j * 64 + (q - 2) * 32);
    const float* wsrc = W1 + o * 128 + q * 32;
    float acc = 0.f;
#pragma unroll
    for (int k = 0; k < 32; ++k) acc += fsrc[k] * wsrc[k];
    acc += __shfl_xor(acc, 1);
    acc += __shfl_xor(acc, 2);
    if (q == 0) m1[w][o] = sigm(acc + b1[o]);
    __syncthreads();
    if (lane < 32) {
        const int o2 = lane >> 4, k = lane & 15;
        float p = m1[w][k] * W2[o2 * 16 + k];
        p += __shfl_xor(p, 1);
        p += __shfl_xor(p, 2);
        p += __shfl_xor(p, 4);
        p += __shfl_xor(p, 8);
        if (k == 0) alphas[e * 2 + o2] = sigm(p + b2[o2]);
    }
}

// ---------------------------------------------------------------------------
// MetaGAT (CSR, MFMA, K-split, PAIR-BATCHED) — R9 version (146 us, best).
// 2 blocks per dst (M-halves). K-split einsum; Si-projections once; pair of
// edges per barrier via 4 rotating Sj LDS slots + register prefetch.
// ---------------------------------------------------------------------------
__global__ __launch_bounds__(256) void gat_csr_kernel(
    const ushort_t* __restrict__ out1,
    const int* __restrict__ degree, const int* __restrict__ rowstart,
    const int* __restrict__ srcids, const int* __restrict__ eids,
    const float* __restrict__ alphas,
    const float* __restrict__ W3, const float* __restrict__ b3,
    float* __restrict__ agg)
{
    __shared__ ushort_t Si[48][72] __attribute__((aligned(16)));     // 6912 B
    __shared__ ushort_t SS[4][48][72] __attribute__((aligned(16)));  // 27648 B

    const int tid = threadIdx.x;
    const int i = blockIdx.x >> 1;
    const int mh = blockIdx.x & 1;        // M-half: local rows map l=(rr>>3)+6*mh
    const int deg = degree[i];
    const int rs = rowstart[i];

    const int wv = tid >> 6;              // N-strip
    const int r = tid & 15;
    const int quad = (tid >> 4) & 3;
    const int n = wv * 16 + r;

    const ushort_t* pi = out1 + i * (NB * LSEQ * HDIM);

    // ---- stage Si (cols 0..63) ----
#pragma unroll
    for (int p = 0; p < 3; ++p) {
        const int u = p * 256 + tid;
        const int rr = u >> 4, c4 = u & 15;
        const int b = rr & 7, l = (rr >> 3) + 6 * mh;
        *(uint2*)&Si[rr][c4 * 4] = *(const uint2*)(pi + (b * 12 + l) * 64 + c4 * 4);
    }

    // ---- pin w_bot columns (k = 64 + ks*32 + quad*8 + jj) in registers ----
    float wba[16], wbb[16], wbc[16];
#pragma unroll
    for (int ks = 0; ks < 2; ++ks)
#pragma unroll
        for (int jj = 0; jj < 8; ++jj) {
            const int m = (64 + ks * 32 + quad * 8 + jj) * 64 + n;
            float2 w2 = ((const float2*)W3)[m];
            wba[ks * 8 + jj] = w2.x; wbb[ks * 8 + jj] = w2.y; wbc[ks * 8 + jj] = b3[m];
        }

    // ---- fixed W-top B-frags for the Si-projection preamble ----
    bf16x8 WtA[2], WtB[2], WtC[2];
#pragma unroll
    for (int ks = 0; ks < 2; ++ks) {
        ushort_t ta[8], tb[8], tc[8];
#pragma unroll
        for (int jj = 0; jj < 8; ++jj) {
            const int m = (ks * 32 + quad * 8 + jj) * 64 + n;
            float2 w2 = ((const float2*)W3)[m];
            ta[jj] = fbf(w2.x); tb[jj] = fbf(w2.y); tc[jj] = fbf(b3[m]);
        }
        WtA[ks] = *(bf16x8*)ta; WtB[ks] = *(bf16x8*)tb; WtC[ks] = *(bf16x8*)tc;
    }

    __syncthreads();   // Si ready

    // ---- preamble: Si-projections PA/PB/PC ----
    f32x4 PA[3], PB[3], PC[3];
#pragma unroll
    for (int mt = 0; mt < 3; ++mt) {
        bf16x8 af0 = *(const bf16x8*)&Si[mt * 16 + r][quad * 8];
        bf16x8 af1 = *(const bf16x8*)&Si[mt * 16 + r][32 + quad * 8];
        f32x4 pa = {0.f, 0.f, 0.f, 0.f};
        f32x4 pb = {0.f, 0.f, 0.f, 0.f};
        f32x4 pc = {0.f, 0.f, 0.f, 0.f};
        pa = __builtin_amdgcn_mfma_f32_16x16x32_bf16(af0, WtA[0], pa, 0, 0, 0);
        pa = __builtin_amdgcn_mfma_f32_16x16x32_bf16(af1, WtA[1], pa, 0, 0, 0);
        pb = __builtin_amdgcn_mfma_f32_16x16x32_bf16(af0, WtB[0], pb, 0, 0, 0);
        pb = __builtin_amdgcn_mfma_f32_16x16x32_bf16(af1, WtB[1], pb, 0, 0, 0);
        pc = __builtin_amdgcn_mfma_f32_16x16x32_bf16(af0, WtC[0], pc, 0, 0, 0);
        pc = __builtin_amdgcn_mfma_f32_16x16x32_bf16(af1, WtC[1], pc, 0, 0, 0);
        PA[mt] = pa; PB[mt] = pb; PC[mt] = pc;
    }

    float accN[3][4];
#pragma unroll
    for (int mt = 0; mt < 3; ++mt)
#pragma unroll
        for (int g2 = 0; g2 < 4; ++g2) accN[mt][g2] = 0.f;

    // process one edge from an LDS tile (K-split einsum + softmax + msg)
    auto process = [&](const ushort_t (*SB)[72], float2 a01) {
        bf16x8 bfrag[2];
#pragma unroll
        for (int ks = 0; ks < 2; ++ks) {
            uint_t tmp[4];
#pragma unroll
            for (int q2 = 0; q2 < 4; ++q2) {
                const int q = ks * 8 + q2 * 2;
                float f0 = fmaf(a01.y, wbb[q], fmaf(a01.x, wba[q], wbc[q]));
                float f1 = fmaf(a01.y, wbb[q + 1], fmaf(a01.x, wba[q + 1], wbc[q + 1]));
                tmp[q2] = pk2(f0, f1);
            }
            bfrag[ks] = *(bf16x8*)tmp;
        }
#pragma unroll
        for (int mt = 0; mt < 3; ++mt) {
            bf16x8 aj0 = *(const bf16x8*)&SB[mt * 16 + r][quad * 8];
            bf16x8 aj1 = *(const bf16x8*)&SB[mt * 16 + r][32 + quad * 8];
            f32x4 acc = {0.f, 0.f, 0.f, 0.f};
            acc = __builtin_amdgcn_mfma_f32_16x16x32_bf16(aj0, bfrag[0], acc, 0, 0, 0);
            acc = __builtin_amdgcn_mfma_f32_16x16x32_bf16(aj1, bfrag[1], acc, 0, 0, 0);
            float v[4];
#pragma unroll
            for (int g2 = 0; g2 < 4; ++g2) {
                float x = acc[g2] + fmaf(a01.x, PA[mt][g2],
                              fmaf(a01.y, PB[mt][g2], PC[mt][g2]));
                v[g2] = x > 0.f ? x : 0.01f * x;   // leaky_relu
            }
            float mx = fmaxf(fmaxf(v[0], v[1]), fmaxf(v[2], v[3]));
            mx = fmaxf(mx, __shfl_xor(mx, 16));
            float s = 0.f;
#pragma unroll
            for (int g2 = 0; g2 < 4; ++g2) { v[g2] = __expf(v[g2] - mx); s += v[g2]; }
            s += __shfl_xor(s, 16);
            const float inv = 1.f / s;
#pragma unroll
            for (int g2 = 0; g2 < 4; ++g2) {
                const int lr = mt * 16 + quad * 4 + g2;
                accN[mt][g2] += v[g2] * inv * bf1(SB[lr][n]);
            }
        }
    };

    // ---- prefetch CSR edges 0,1 into registers ----
    uint2 pfA[3], pfB[3];
    {
        const ushort_t* pA = out1 + ((deg >= 1) ? srcids[rs] : 0) * (NB * LSEQ * HDIM);
        const ushort_t* pB = out1 + ((deg >= 2) ? srcids[rs + 1] : 0) * (NB * LSEQ * HDIM);
#pragma unroll
        for (int p = 0; p < 3; ++p) {
            const int u = p * 256 + tid;
            const int rr = u >> 4, c4 = u & 15;
            const int b = rr & 7, l = (rr >> 3) + 6 * mh;
            pfA[p] = *(const uint2*)(pA + (b * 12 + l) * 64 + c4 * 4);
            pfB[p] = *(const uint2*)(pB + (b * 12 + l) * 64 + c4 * 4);
        }
    }

    // ---- self loop (uses Si tile directly) ----
    process((const ushort_t (*)[72])Si, *(const float2*)(alphas + (NEDGE + i) * 2));

    const int npairs = (deg + 1) >> 1;
    for (int pk = 0; pk < npairs; ++pk) {
        ushort_t (*SA)[72] = SS[2 * (pk & 1)];
        ushort_t (*SB)[72] = SS[2 * (pk & 1) + 1];
#pragma unroll
        for (int p = 0; p < 3; ++p) {
            const int u = p * 256 + tid;
            const int rr = u >> 4, c4 = u & 15;
            *(uint2*)&SA[rr][c4 * 4] = pfA[p];
            *(uint2*)&SB[rr][c4 * 4] = pfB[p];
        }
        const int base = pk * 2;
        const float2 aA = *(const float2*)(alphas + eids[rs + base] * 2);
        const bool hasB = (base + 1) < deg;
        float2 aB = float2{0.f, 0.f};
        if (hasB) aB = *(const float2*)(alphas + eids[rs + base + 1] * 2);
        __syncthreads();   // pair tiles ready (slots from pair pk-1 fully read pre-barrier)

        // prefetch next pair under this pair's compute
        if (base + 2 < deg) {
            const ushort_t* pA = out1 + srcids[rs + base + 2] * (NB * LSEQ * HDIM);
#pragma unroll
            for (int p = 0; p < 3; ++p) {
                const int u = p * 256 + tid;
                const int rr = u >> 4, c4 = u & 15;
                const int b = rr & 7, l = (rr >> 3) + 6 * mh;
                pfA[p] = *(const uint2*)(pA + (b * 12 + l) * 64 + c4 * 4);
            }
        }
        if (base + 3 < deg) {
            const ushort_t* pB = out1 + srcids[rs + base + 3] * (NB * LSEQ * HDIM);
#pragma unroll
            for (int p = 0; p < 3; ++p) {
                const int u = p * 256 + tid;
                const int rr = u >> 4, c4 = u & 15;
                const int b = rr & 7, l = (rr >> 3) + 6 * mh;
                pfB[p] = *(const uint2*)(pB + (b * 12 + l) * 64 + c4 * 4);
            }
        }

        process((const ushort_t (*)[72])SA, aA);
        if (hasB) process((const ushort_t (*)[72])SB, aB);
    }

    // single non-atomic store of this half-node's aggregate
#pragma unroll
    for (int mt = 0; mt < 3; ++mt)
#pragma unroll
        for (int g2 = 0; g2 < 4; ++g2) {
            const int gr = 48 * mh + mt * 16 + quad * 4 + g2;  // = l*8 + b
            const int b = gr & 7, l = gr >> 3;
            agg[(i * 96 + b * 12 + l) * 64 + n] = accN[mt][g2];
        }
}

// ---------------------------------------------------------------------------
// GRU2: gi AND gh via MFMA; x_t = relu(agg) staged bf16, next-step global
// load software-pipelined under the MFMAs. 32 seqs / 4 waves per block.
// ---------------------------------------------------------------------------
__global__ __launch_bounds__(256) void gru2_kernel(
    const float* __restrict__ agg, const float* __restrict__ Wih,
    const float* __restrict__ Whh, const float* __restrict__ bih,
    const float* __restrict__ bhh, float* __restrict__ h2out)
{
    __shared__ ushort_t H[32][72] __attribute__((aligned(16)));  // 4608 B
    __shared__ ushort_t X[32][72] __attribute__((aligned(16)));  // 4608 B

    const int tid = threadIdx.x;
    const int nw = tid >> 6;             // N-strip 0..3
    const int c = tid & 15;
    const int quad = (tid >> 4) & 3;
    const int j = nw * 16 + c;
    const int s0 = blockIdx.x * 32;
    const int sl = tid >> 3, k0 = (tid & 7) * 8;   // X staging: 32 rows x 64

    *(uint4*)&H[tid & 31][(tid >> 5) * 8] = uint4{0, 0, 0, 0};

    bf16x8 Bh[3][2], Bi[3][2];
    float bi[3], bh[3];
#pragma unroll
    for (int g = 0; g < 3; ++g) {
        const int row = g * 64 + j;
        bi[g] = bih[row]; bh[g] = bhh[row];
#pragma unroll
        for (int ks = 0; ks < 2; ++ks) {
            const float* wp = Whh + (row << 6) + ks * 32 + quad * 8;
            float4 wa = *(const float4*)wp;
            float4 wb = *(const float4*)(wp + 4);
            ushort_t tmp[8];
            tmp[0] = fbf(wa.x); tmp[1] = fbf(wa.y); tmp[2] = fbf(wa.z); tmp[3] = fbf(wa.w);
            tmp[4] = fbf(wb.x); tmp[5] = fbf(wb.y); tmp[6] = fbf(wb.z); tmp[7] = fbf(wb.w);
            Bh[g][ks] = *(bf16x8*)tmp;
            const float* wp2 = Wih + (row << 6) + ks * 32 + quad * 8;
            float4 va = *(const float4*)wp2;
            float4 vb = *(const float4*)(wp2 + 4);
            tmp[0] = fbf(va.x); tmp[1] = fbf(va.y); tmp[2] = fbf(va.z); tmp[3] = fbf(va.w);
            tmp[4] = fbf(vb.x); tmp[5] = fbf(vb.y); tmp[6] = fbf(vb.z); tmp[7] = fbf(vb.w);
            Bi[g][ks] = *(bf16x8*)tmp;
        }
    }

    float hold[2][4];
#pragma unroll
    for (int mt = 0; mt < 2; ++mt)
#pragma unroll
        for (int rg = 0; rg < 4; ++rg) hold[mt][rg] = 0.f;

    float xr[8];
    {
        const float* gp = agg + (s0 + sl) * (LSEQ * HDIM) + k0;
        *(float4*)&xr[0] = *(const float4*)gp;
        *(float4*)&xr[4] = *(const float4*)(gp + 4);
    }

    for (int t = 0; t < LSEQ; ++t) {
        {
            ushort_t xs[8];
#pragma unroll
            for (int q = 0; q < 8; ++q) xs[q] = fbf(xr[q] > 0.f ? xr[q] : 0.f);
            *(uint4*)&X[sl][k0] = *(uint4*)xs;
        }
        __syncthreads();   // A: X_t + H_t visible
        bf16x8 ah0[2], ah1[2], ax0[2], ax1[2];
#pragma unroll
        for (int mt = 0; mt < 2; ++mt) {
            const int mrow = mt * 16 + c;
            ah0[mt] = *(const bf16x8*)&H[mrow][quad * 8];
            ah1[mt] = *(const bf16x8*)&H[mrow][32 + quad * 8];
            ax0[mt] = *(const bf16x8*)&X[mrow][quad * 8];
            ax1[mt] = *(const bf16x8*)&X[mrow][32 + quad * 8];
        }
        if (t < LSEQ - 1) {
            const float* gp = agg + (s0 + sl) * (LSEQ * HDIM) + (t + 1) * HDIM + k0;
            *(float4*)&xr[0] = *(const float4*)gp;
            *(float4*)&xr[4] = *(const float4*)(gp + 4);
        }
        ushort_t hnb[2][4];
#pragma unroll
        for (int mt = 0; mt < 2; ++mt) {
            f32x4 gh[3], gi[3];
#pragma unroll
            for (int g = 0; g < 3; ++g) {
                f32x4 acc = {0.f, 0.f, 0.f, 0.f};
                acc = __builtin_amdgcn_mfma_f32_16x16x32_bf16(ah0[mt], Bh[g][0], acc, 0, 0, 0);
                acc = __builtin_amdgcn_mfma_f32_16x16x32_bf16(ah1[mt], Bh[g][1], acc, 0, 0, 0);
                gh[g] = acc;
                f32x4 acc2 = {0.f, 0.f, 0.f, 0.f};
                acc2 = __builtin_amdgcn_mfma_f32_16x16x32_bf16(ax0[mt], Bi[g][0], acc2, 0, 0, 0);
                acc2 = __builtin_amdgcn_mfma_f32_16x16x32_bf16(ax1[mt], Bi[g][1], acc2, 0, 0, 0);
                gi[g] = acc2;
            }
#pragma unroll
            for (int rg = 0; rg < 4; ++rg) {
                float r = sigm(bi[0] + gi[0][rg] + bh[0] + gh[0][rg]);
                float z = sigm(bi[1] + gi[1][rg] + bh[1] + gh[1][rg]);
                float n = tanh_fast(bi[2] + gi[2][rg] + r * (bh[2] + gh[2][rg]));
                float hv = (1.f - z) * n + z * hold[mt][rg];
                hold[mt][rg] = hv;
                hnb[mt][rg] = fbf(hv);
            }
        }
        __syncthreads();   // B: all reads done
#pragma unroll
        for (int mt = 0; mt < 2; ++mt)
#pragma unroll
            for (int rg = 0; rg < 4; ++rg) {
                const int sloc = mt * 16 + quad * 4 + rg;
                H[sloc][j] = hnb[mt][rg];
            }
    }
#pragma unroll
    for (int mt = 0; mt < 2; ++mt)
#pragma unroll
        for (int rg = 0; rg < 4; ++rg) {
            const int sloc = mt * 16 + quad * 4 + rg;
            h2out[(s0 + sloc) * HDIM + j] = hold[mt][rg];
        }
}

extern "C" void kernel_launch(void* const* d_in, const int* in_sizes, int n_in,
                              void* d_out, int out_size, void* d_ws, size_t ws_size,
                              hipStream_t stream)
{
    const float* data     = (const float*)d_in[0];
    const float* features = (const float*)d_in[1];
    const int*   edges    = (const int*)d_in[2];
    const float* Wih1     = (const float*)d_in[3];
    const float* Whh1     = (const float*)d_in[4];
    const float* bih1     = (const float*)d_in[5];
    const float* bhh1     = (const float*)d_in[6];
    const float* W1       = (const float*)d_in[7];
    const float* b1       = (const float*)d_in[8];
    const float* W2       = (const float*)d_in[9];
    const float* b2       = (const float*)d_in[10];
    const float* W3       = (const float*)d_in[11];
    const float* b3       = (const float*)d_in[12];
    const float* Wih2     = (const float*)d_in[13];
    const float* Whh2     = (const float*)d_in[14];
    const float* bih2     = (const float*)d_in[15];
    const float* bhh2     = (const float*)d_in[16];

    float*    out  = (float*)d_out;
    char*     ws   = (char*)d_ws;
    ushort_t* out1 = (ushort_t*)ws;                    // bf16 intermediate
    float*    agg  = (float*)(ws + OUT1_BYTES);        // fp32 GAT output
    int*      meta = (int*)(ws + OUT1_BYTES + AGG_BYTES);
    int*   degree   = meta;                       // [2000]
    int*   cursor   = meta + NNODE;               // [2000]
    int*   rowstart = meta + 2 * NNODE;           // [2000]
    int*   srcids   = meta + 3 * NNODE;           // [16000]
    int*   eids     = meta + 3 * NNODE + NEDGE;   // [16000]
    float* alphas   = (float*)(meta + 3 * NNODE + 2 * NEDGE);  // [36000]

    hipMemsetAsync(meta, 0, 2 * NNODE * sizeof(int), stream);   // degree+cursor

    count_kernel<<<(NEDGE + 255) / 256, 256, 0, stream>>>(edges, degree);
    scan_kernel<<<1, 256, 0, stream>>>(degree, rowstart);
    scatter_kernel<<<(NEDGE + 255) / 256, 256, 0, stream>>>(edges, rowstart, cursor,
                                                            srcids, eids);
    alpha_kernel<<<(NEDGE + NNODE) / 4, 256, 0, stream>>>(features, edges,
                                                          W1, b1, W2, b2, alphas);

    gru1_kernel<<<NSEQ / 32, 256, 0, stream>>>(data, Wih1, Whh1, bih1, bhh1, out1, out);
    gat_csr_kernel<<<2 * NNODE, 256, 0, stream>>>(out1, degree, rowstart, srcids, eids,
                                                  alphas, W3, b3, agg);
    gru2_kernel<<<NSEQ / 32, 256, 0, stream>>>(agg, Wih2, Whh2, bih2, bhh2,
                                               out + NNODE * NB * HDIM);
}

// Round 12
// 320.761 us; speedup vs baseline: 1.1729x; 1.0563x over previous
//
#include <hip/hip_runtime.h>
#include <hip/hip_bf16.h>

typedef unsigned short ushort_t;
typedef unsigned int uint_t;
typedef __attribute__((ext_vector_type(8))) short bf16x8;
typedef __attribute__((ext_vector_type(4))) float f32x4;

#define NNODE 2000
#define NB 8
#define LSEQ 12
#define HDIM 64
#define NEDGE 16000
#define NSEQ (NNODE * NB)            // 16000 sequences
#define OUT1_ELEMS (NNODE * NB * LSEQ * HDIM)   // 12,288,000
#define OUT1_BYTES (OUT1_ELEMS * 2)             // bf16: 24,576,000
#define AGG_BYTES  (OUT1_ELEMS * 2)             // bf16 now: 24,576,000

__device__ __forceinline__ float bf1(ushort_t u) { return __uint_as_float(((uint_t)u) << 16); }
__device__ __forceinline__ ushort_t fbf(float f) {
    uint_t x = __float_as_uint(f);
    uint_t r = x + 0x7fffu + ((x >> 16) & 1u);   // RNE
    return (ushort_t)(r >> 16);
}
__device__ __forceinline__ uint_t pk2(float lo, float hi) {
    __hip_bfloat162 t = __float22bfloat162_rn(float2{lo, hi});
    return *(uint_t*)&t;   // low ushort = bf(lo)
}
__device__ __forceinline__ float sigm(float x) { return 1.f / (1.f + __expf(-x)); }
__device__ __forceinline__ float tanh_fast(float x) { return 2.f / (1.f + __expf(-2.f * x)) - 1.f; }

// ===========================================================================
// MFMA geometry (HW-verified R3): A[m=lane&15][k=quad*8+jj];
// B[k=ks*32+quad*8+jj][n=lane&15]; C row(M)=quad*4+reg, col(N)=lane&15.
// ===========================================================================

// ---------------------------------------------------------------------------
// GRU1: x_t is only 2-wide -> gi on VALU; gh via MFMA. out1 bf16 per step.
// ---------------------------------------------------------------------------
__global__ __launch_bounds__(256) void gru1_kernel(
    const float* __restrict__ data, const float* __restrict__ Wih,
    const float* __restrict__ Whh, const float* __restrict__ bih,
    const float* __restrict__ bhh, ushort_t* __restrict__ out1,
    float* __restrict__ h1out)
{
    __shared__ ushort_t H[32][72] __attribute__((aligned(16)));  // 4608 B
    __shared__ float XD[32][26];                                 // 3328 B

    const int tid = threadIdx.x;
    const int nw = tid >> 6;             // N-strip 0..3
    const int c = tid & 15;
    const int quad = (tid >> 4) & 3;
    const int j = nw * 16 + c;
    const int s0 = blockIdx.x * 32;

    *(uint4*)&H[tid & 31][(tid >> 5) * 8] = uint4{0, 0, 0, 0};
#pragma unroll
    for (int p = 0; p < 3; ++p) {
        const int flat = p * 256 + tid;     // 0..767
        const int sl = flat / 24, q = flat - sl * 24;
        XD[sl][q] = data[(s0 + sl) * 24 + q];
    }

    bf16x8 Bh[3][2];
    float wi0[3], wi1[3], bi[3], bh[3];
#pragma unroll
    for (int g = 0; g < 3; ++g) {
        const int row = g * 64 + j;
        float2 wi = *(const float2*)(Wih + row * 2);
        wi0[g] = wi.x; wi1[g] = wi.y;
        bi[g] = bih[row]; bh[g] = bhh[row];
#pragma unroll
        for (int ks = 0; ks < 2; ++ks) {
            const float* wp = Whh + (row << 6) + ks * 32 + quad * 8;
            float4 wa = *(const float4*)wp;
            float4 wb = *(const float4*)(wp + 4);
            ushort_t tmp[8];
            tmp[0] = fbf(wa.x); tmp[1] = fbf(wa.y); tmp[2] = fbf(wa.z); tmp[3] = fbf(wa.w);
            tmp[4] = fbf(wb.x); tmp[5] = fbf(wb.y); tmp[6] = fbf(wb.z); tmp[7] = fbf(wb.w);
            Bh[g][ks] = *(bf16x8*)tmp;
        }
    }

    float hold[2][4];
#pragma unroll
    for (int mt = 0; mt < 2; ++mt)
#pragma unroll
        for (int rg = 0; rg < 4; ++rg) hold[mt][rg] = 0.f;

    for (int t = 0; t < LSEQ; ++t) {
        __syncthreads();   // A: H (+XD at t=0) visible
        bf16x8 a0[2], a1[2];
#pragma unroll
        for (int mt = 0; mt < 2; ++mt) {
            a0[mt] = *(const bf16x8*)&H[mt * 16 + c][quad * 8];
            a1[mt] = *(const bf16x8*)&H[mt * 16 + c][32 + quad * 8];
        }
        ushort_t hnb[2][4];
#pragma unroll
        for (int mt = 0; mt < 2; ++mt) {
            f32x4 gh[3];
#pragma unroll
            for (int g = 0; g < 3; ++g) {
                f32x4 acc = {0.f, 0.f, 0.f, 0.f};
                acc = __builtin_amdgcn_mfma_f32_16x16x32_bf16(a0[mt], Bh[g][0], acc, 0, 0, 0);
                acc = __builtin_amdgcn_mfma_f32_16x16x32_bf16(a1[mt], Bh[g][1], acc, 0, 0, 0);
                gh[g] = acc;
            }
#pragma unroll
            for (int rg = 0; rg < 4; ++rg) {
                const int sloc = mt * 16 + quad * 4 + rg;
                float2 xp = *(const float2*)&XD[sloc][2 * t];
                float gr = bh[0] + gh[0][rg];
                float gz = bh[1] + gh[1][rg];
                float gn = bh[2] + gh[2][rg];
                float ir = bi[0] + wi0[0] * xp.x + wi1[0] * xp.y;
                float iz = bi[1] + wi0[1] * xp.x + wi1[1] * xp.y;
                float in = bi[2] + wi0[2] * xp.x + wi1[2] * xp.y;
                float r = sigm(ir + gr);
                float z = sigm(iz + gz);
                float n = tanh_fast(in + r * gn);
                float hv = (1.f - z) * n + z * hold[mt][rg];
                hold[mt][rg] = hv;
                hnb[mt][rg] = fbf(hv);
            }
        }
        __syncthreads();   // B: all A-frag reads done
#pragma unroll
        for (int mt = 0; mt < 2; ++mt)
#pragma unroll
            for (int rg = 0; rg < 4; ++rg) {
                const int sloc = mt * 16 + quad * 4 + rg;
                H[sloc][j] = hnb[mt][rg];
                out1[(s0 + sloc) * (LSEQ * HDIM) + t * HDIM + j] = hnb[mt][rg];
            }
    }
#pragma unroll
    for (int mt = 0; mt < 2; ++mt)
#pragma unroll
        for (int rg = 0; rg < 4; ++rg) {
            const int sloc = mt * 16 + quad * 4 + rg;
            h1out[(s0 + sloc) * HDIM + j] = hold[mt][rg];
        }
}

// ---------------------------------------------------------------------------
// CSR helpers.
// ---------------------------------------------------------------------------
__global__ __launch_bounds__(256) void count_kernel(const int* __restrict__ edges,
                                                    int* __restrict__ degree)
{
    const int e = blockIdx.x * 256 + threadIdx.x;
    if (e < NEDGE) atomicAdd(&degree[edges[NEDGE + e]], 1);
}

// parallel scan: per-thread partial -> wave shuffle scan -> cross-wave via LDS
__global__ __launch_bounds__(256) void scan_kernel(const int* __restrict__ degree,
                                                   int* __restrict__ rowstart)
{
    __shared__ int wsum[4];
    const int t = threadIdx.x;
    const int lane = t & 63, w = t >> 6;
    int d[8];
    int s = 0;
#pragma unroll
    for (int q = 0; q < 8; ++q) {
        const int idx = t * 8 + q;
        d[q] = (idx < NNODE) ? degree[idx] : 0;
        s += d[q];
    }
    int v = s;   // inclusive wave scan
#pragma unroll
    for (int off = 1; off < 64; off <<= 1) {
        int u = __shfl_up(v, off);
        if (lane >= off) v += u;
    }
    if (lane == 63) wsum[w] = v;
    __syncthreads();
    int base = 0;
    for (int k = 0; k < 4; ++k) if (k < w) base += wsum[k];
    int run = base + v - s;   // exclusive prefix for this thread
#pragma unroll
    for (int q = 0; q < 8; ++q) {
        const int idx = t * 8 + q;
        if (idx < NNODE) { rowstart[idx] = run; run += d[q]; }
    }
}

__global__ __launch_bounds__(256) void scatter_kernel(const int* __restrict__ edges,
                                                      const int* __restrict__ rowstart,
                                                      int* __restrict__ cursor,
                                                      int* __restrict__ srcids,
                                                      int* __restrict__ eids)
{
    const int e = blockIdx.x * 256 + threadIdx.x;
    if (e < NEDGE) {
        const int d = edges[NEDGE + e];
        const int pos = atomicAdd(&cursor[d], 1);
        srcids[rowstart[d] + pos] = edges[e];   // src node
        eids[rowstart[d] + pos] = e;            // edge id (alpha index)
    }
}

// ---------------------------------------------------------------------------
// Per-edge MLP hoisted: alphas[2e] = (a0,a1), all 18000 edges incl. self.
// ---------------------------------------------------------------------------
__global__ __launch_bounds__(256) void alpha_kernel(
    const float* __restrict__ features, const int* __restrict__ edges,
    const float* __restrict__ W1, const float* __restrict__ b1,
    const float* __restrict__ W2, const float* __restrict__ b2,
    float* __restrict__ alphas)
{
    __shared__ float m1[4][16];
    const int tid = threadIdx.x;
    const int w = tid >> 6, lane = tid & 63;
    const int e = blockIdx.x * 4 + w;           // grid sized exactly 18000/4
    int i, j;
    if (e < NEDGE) { j = edges[e]; i = edges[NEDGE + e]; }
    else { i = j = e - NEDGE; }

    const int o = lane >> 2, q = lane & 3;      // 16 outputs x 4 partials
    const float* fsrc = (q < 2) ? (features + i * 64 + q * 32)
                                : (features + j * 64 + (q - 2) * 32);
    const float* wsrc = W1 + o * 128 + q * 32;
    float acc = 0.f;
#pragma unroll
    for (int k = 0; k < 32; ++k) acc += fsrc[k] * wsrc[k];
    acc += __shfl_xor(acc, 1);
    acc += __shfl_xor(acc, 2);
    if (q == 0) m1[w][o] = sigm(acc + b1[o]);
    __syncthreads();
    if (lane < 32) {
        const int o2 = lane >> 4, k = lane & 15;
        float p = m1[w][k] * W2[o2 * 16 + k];
        p += __shfl_xor(p, 1);
        p += __shfl_xor(p, 2);
        p += __shfl_xor(p, 4);
        p += __shfl_xor(p, 8);
        if (k == 0) alphas[e * 2 + o2] = sigm(p + b2[o2]);
    }
}

// ---------------------------------------------------------------------------
// MetaGAT (CSR, MFMA, K-split, PAIR-BATCHED, 3-way node split): grid
// (NNODE, 3); blockIdx.y = M-third (32 rows, l = (rr>>3)+4*mh). All loop
// offsets precomputed (global stage, LDS stage, A-frag, msg). Pair of edges
// per barrier via 4 rotating 32x72 Sj slots + register prefetch. agg bf16.
// ---------------------------------------------------------------------------
__global__ __launch_bounds__(256) void gat_csr_kernel(
    const ushort_t* __restrict__ out1,
    const int* __restrict__ degree, const int* __restrict__ rowstart,
    const int* __restrict__ srcids, const int* __restrict__ eids,
    const float* __restrict__ alphas,
    const float* __restrict__ W3, const float* __restrict__ b3,
    ushort_t* __restrict__ agg)
{
    __shared__ ushort_t Si[32][72] __attribute__((aligned(16)));     // 4608 B
    __shared__ ushort_t SS[4][32][72] __attribute__((aligned(16)));  // 18432 B

    const int tid = threadIdx.x;
    const int i = blockIdx.x;
    const int mh = blockIdx.y;            // M-third
    const int deg = degree[i];
    const int rs = rowstart[i];

    const int wv = tid >> 6;              // N-strip
    const int r = tid & 15;
    const int quad = (tid >> 4) & 3;
    const int n = wv * 16 + r;

    // ---- precomputed invariant offsets ----
    int glo[2], lso[2];                   // staging: global elem / LDS elem
#pragma unroll
    for (int p = 0; p < 2; ++p) {
        const int u = p * 256 + tid;      // 0..511
        const int rr = u >> 4, c4 = u & 15;
        const int b = rr & 7, l = (rr >> 3) + 4 * mh;
        glo[p] = (b * 12 + l) * 64 + c4 * 4;
        lso[p] = rr * 72 + c4 * 4;
    }
    int afo[2][2];                        // A-frag LDS elem offsets
#pragma unroll
    for (int mt = 0; mt < 2; ++mt) {
        afo[mt][0] = (mt * 16 + r) * 72 + quad * 8;
        afo[mt][1] = afo[mt][0] + 32;
    }
    int mgo[8];                           // msg LDS elem offsets
#pragma unroll
    for (int mt = 0; mt < 2; ++mt)
#pragma unroll
        for (int g2 = 0; g2 < 4; ++g2)
            mgo[mt * 4 + g2] = (mt * 16 + quad * 4 + g2) * 72 + n;

    const ushort_t* pi = out1 + i * (NB * LSEQ * HDIM);
    ushort_t* const sbase = &SS[0][0][0];

    // ---- stage Si ----
#pragma unroll
    for (int p = 0; p < 2; ++p)
        *(uint2*)(&Si[0][0] + lso[p]) = *(const uint2*)(pi + glo[p]);

    // ---- pin w_bot columns ----
    float wba[16], wbb[16], wbc[16];
#pragma unroll
    for (int ks = 0; ks < 2; ++ks)
#pragma unroll
        for (int jj = 0; jj < 8; ++jj) {
            const int m = (64 + ks * 32 + quad * 8 + jj) * 64 + n;
            float2 w2 = ((const float2*)W3)[m];
            wba[ks * 8 + jj] = w2.x; wbb[ks * 8 + jj] = w2.y; wbc[ks * 8 + jj] = b3[m];
        }

    // ---- fixed W-top B-frags ----
    bf16x8 WtA[2], WtB[2], WtC[2];
#pragma unroll
    for (int ks = 0; ks < 2; ++ks) {
        ushort_t ta[8], tb[8], tc[8];
#pragma unroll
        for (int jj = 0; jj < 8; ++jj) {
            const int m = (ks * 32 + quad * 8 + jj) * 64 + n;
            float2 w2 = ((const float2*)W3)[m];
            ta[jj] = fbf(w2.x); tb[jj] = fbf(w2.y); tc[jj] = fbf(b3[m]);
        }
        WtA[ks] = *(bf16x8*)ta; WtB[ks] = *(bf16x8*)tb; WtC[ks] = *(bf16x8*)tc;
    }

    __syncthreads();   // Si ready

    // ---- preamble: Si-projections PA/PB/PC ----
    f32x4 PA[2], PB[2], PC[2];
#pragma unroll
    for (int mt = 0; mt < 2; ++mt) {
        bf16x8 af0 = *(const bf16x8*)(&Si[0][0] + afo[mt][0]);
        bf16x8 af1 = *(const bf16x8*)(&Si[0][0] + afo[mt][1]);
        f32x4 pa = {0.f, 0.f, 0.f, 0.f};
        f32x4 pb = {0.f, 0.f, 0.f, 0.f};
        f32x4 pc = {0.f, 0.f, 0.f, 0.f};
        pa = __builtin_amdgcn_mfma_f32_16x16x32_bf16(af0, WtA[0], pa, 0, 0, 0);
        pa = __builtin_amdgcn_mfma_f32_16x16x32_bf16(af1, WtA[1], pa, 0, 0, 0);
        pb = __builtin_amdgcn_mfma_f32_16x16x32_bf16(af0, WtB[0], pb, 0, 0, 0);
        pb = __builtin_amdgcn_mfma_f32_16x16x32_bf16(af1, WtB[1], pb, 0, 0, 0);
        pc = __builtin_amdgcn_mfma_f32_16x16x32_bf16(af0, WtC[0], pc, 0, 0, 0);
        pc = __builtin_amdgcn_mfma_f32_16x16x32_bf16(af1, WtC[1], pc, 0, 0, 0);
        PA[mt] = pa; PB[mt] = pb; PC[mt] = pc;
    }

    float accN[2][4];
#pragma unroll
    for (int mt = 0; mt < 2; ++mt)
#pragma unroll
        for (int g2 = 0; g2 < 4; ++g2) accN[mt][g2] = 0.f;

    // process one edge from an LDS tile (K-split einsum + softmax + msg)
    auto process = [&](const ushort_t* SB, float2 a01) {
        bf16x8 bfrag[2];
#pragma unroll
        for (int ks = 0; ks < 2; ++ks) {
            uint_t tmp[4];
#pragma unroll
            for (int q2 = 0; q2 < 4; ++q2) {
                const int q = ks * 8 + q2 * 2;
                float f0 = fmaf(a01.y, wbb[q], fmaf(a01.x, wba[q], wbc[q]));
                float f1 = fmaf(a01.y, wbb[q + 1], fmaf(a01.x, wba[q + 1], wbc[q + 1]));
                tmp[q2] = pk2(f0, f1);
            }
            bfrag[ks] = *(bf16x8*)tmp;
        }
#pragma unroll
        for (int mt = 0; mt < 2; ++mt) {
            bf16x8 aj0 = *(const bf16x8*)(SB + afo[mt][0]);
            bf16x8 aj1 = *(const bf16x8*)(SB + afo[mt][1]);
            f32x4 acc = {0.f, 0.f, 0.f, 0.f};
            acc = __builtin_amdgcn_mfma_f32_16x16x32_bf16(aj0, bfrag[0], acc, 0, 0, 0);
            acc = __builtin_amdgcn_mfma_f32_16x16x32_bf16(aj1, bfrag[1], acc, 0, 0, 0);
            float v[4];
#pragma unroll
            for (int g2 = 0; g2 < 4; ++g2) {
                float x = acc[g2] + fmaf(a01.x, PA[mt][g2],
                              fmaf(a01.y, PB[mt][g2], PC[mt][g2]));
                v[g2] = x > 0.f ? x : 0.01f * x;   // leaky_relu
            }
            float mx = fmaxf(fmaxf(v[0], v[1]), fmaxf(v[2], v[3]));
            mx = fmaxf(mx, __shfl_xor(mx, 16));
            float s = 0.f;
#pragma unroll
            for (int g2 = 0; g2 < 4; ++g2) { v[g2] = __expf(v[g2] - mx); s += v[g2]; }
            s += __shfl_xor(s, 16);
            const float inv = 1.f / s;
#pragma unroll
            for (int g2 = 0; g2 < 4; ++g2)
                accN[mt][g2] += v[g2] * inv * bf1(SB[mgo[mt * 4 + g2]]);
        }
    };

    // ---- prefetch CSR edges 0,1 into registers ----
    uint2 pfA[2], pfB[2];
    {
        const ushort_t* pA = out1 + ((deg >= 1) ? srcids[rs] : 0) * (NB * LSEQ * HDIM);
        const ushort_t* pB = out1 + ((deg >= 2) ? srcids[rs + 1] : 0) * (NB * LSEQ * HDIM);
#pragma unroll
        for (int p = 0; p < 2; ++p) {
            pfA[p] = *(const uint2*)(pA + glo[p]);
            pfB[p] = *(const uint2*)(pB + glo[p]);
        }
    }

    // ---- self loop (uses Si tile directly) ----
    process(&Si[0][0], *(const float2*)(alphas + (NEDGE + i) * 2));

    const int npairs = (deg + 1) >> 1;
    for (int pk = 0; pk < npairs; ++pk) {
        ushort_t* SA = sbase + (2 * (pk & 1)) * (32 * 72);
        ushort_t* SB = SA + 32 * 72;
#pragma unroll
        for (int p = 0; p < 2; ++p) {
            *(uint2*)(SA + lso[p]) = pfA[p];
            *(uint2*)(SB + lso[p]) = pfB[p];
        }
        const int base = pk * 2;
        const float2 aA = *(const float2*)(alphas + eids[rs + base] * 2);
        const bool hasB = (base + 1) < deg;
        float2 aB = float2{0.f, 0.f};
        if (hasB) aB = *(const float2*)(alphas + eids[rs + base + 1] * 2);
        __syncthreads();   // pair tiles ready (pk-1 slots fully read pre-barrier)

        // prefetch next pair under this pair's compute
        if (base + 2 < deg) {
            const ushort_t* pA = out1 + srcids[rs + base + 2] * (NB * LSEQ * HDIM);
#pragma unroll
            for (int p = 0; p < 2; ++p) pfA[p] = *(const uint2*)(pA + glo[p]);
        }
        if (base + 3 < deg) {
            const ushort_t* pB = out1 + srcids[rs + base + 3] * (NB * LSEQ * HDIM);
#pragma unroll
            for (int p = 0; p < 2; ++p) pfB[p] = *(const uint2*)(pB + glo[p]);
        }

        process(SA, aA);
        if (hasB) process(SB, aB);
    }

    // single non-atomic bf16 store of this third-node's aggregate
#pragma unroll
    for (int mt = 0; mt < 2; ++mt)
#pragma unroll
        for (int g2 = 0; g2 < 4; ++g2) {
            const int lr = mt * 16 + quad * 4 + g2;      // local row 0..31
            const int b = lr & 7, l = (lr >> 3) + 4 * mh;
            agg[(i * 96 + b * 12 + l) * 64 + n] = fbf(accN[mt][g2]);
        }
}

// ---------------------------------------------------------------------------
// GRU2: gi AND gh via MFMA; x_t = relu(agg bf16), next-step global load
// software-pipelined under the MFMAs. 32 seqs / 4 waves per block.
// ---------------------------------------------------------------------------
__global__ __launch_bounds__(256) void gru2_kernel(
    const ushort_t* __restrict__ agg, const float* __restrict__ Wih,
    const float* __restrict__ Whh, const float* __restrict__ bih,
    const float* __restrict__ bhh, float* __restrict__ h2out)
{
    __shared__ ushort_t H[32][72] __attribute__((aligned(16)));  // 4608 B
    __shared__ ushort_t X[32][72] __attribute__((aligned(16)));  // 4608 B

    const int tid = threadIdx.x;
    const int nw = tid >> 6;             // N-strip 0..3
    const int c = tid & 15;
    const int quad = (tid >> 4) & 3;
    const int j = nw * 16 + c;
    const int s0 = blockIdx.x * 32;
    const int sl = tid >> 3, k0 = (tid & 7) * 8;   // X staging: 32 rows x 64

    *(uint4*)&H[tid & 31][(tid >> 5) * 8] = uint4{0, 0, 0, 0};

    bf16x8 Bh[3][2], Bi[3][2];
    float bi[3], bh[3];
#pragma unroll
    for (int g = 0; g < 3; ++g) {
        const int row = g * 64 + j;
        bi[g] = bih[row]; bh[g] = bhh[row];
#pragma unroll
        for (int ks = 0; ks < 2; ++ks) {
            const float* wp = Whh + (row << 6) + ks * 32 + quad * 8;
            float4 wa = *(const float4*)wp;
            float4 wb = *(const float4*)(wp + 4);
            ushort_t tmp[8];
            tmp[0] = fbf(wa.x); tmp[1] = fbf(wa.y); tmp[2] = fbf(wa.z); tmp[3] = fbf(wa.w);
            tmp[4] = fbf(wb.x); tmp[5] = fbf(wb.y); tmp[6] = fbf(wb.z); tmp[7] = fbf(wb.w);
            Bh[g][ks] = *(bf16x8*)tmp;
            const float* wp2 = Wih + (row << 6) + ks * 32 + quad * 8;
            float4 va = *(const float4*)wp2;
            float4 vb = *(const float4*)(wp2 + 4);
            tmp[0] = fbf(va.x); tmp[1] = fbf(va.y); tmp[2] = fbf(va.z); tmp[3] = fbf(va.w);
            tmp[4] = fbf(vb.x); tmp[5] = fbf(vb.y); tmp[6] = fbf(vb.z); tmp[7] = fbf(vb.w);
            Bi[g][ks] = *(bf16x8*)tmp;
        }
    }

    float hold[2][4];
#pragma unroll
    for (int mt = 0; mt < 2; ++mt)
#pragma unroll
        for (int rg = 0; rg < 4; ++rg) hold[mt][rg] = 0.f;

    ushort_t xr[8];
    {
        const ushort_t* gp = agg + (s0 + sl) * (LSEQ * HDIM) + k0;
        *(uint4*)xr = *(const uint4*)gp;
    }

    for (int t = 0; t < LSEQ; ++t) {
        {
            ushort_t xs[8];
#pragma unroll
            for (int q = 0; q < 8; ++q) xs[q] = (xr[q] & 0x8000u) ? (ushort_t)0 : xr[q];
            *(uint4*)&X[sl][k0] = *(uint4*)xs;
        }
        __syncthreads();   // A: X_t + H_t visible
        bf16x8 ah0[2], ah1[2], ax0[2], ax1[2];
#pragma unroll
        for (int mt = 0; mt < 2; ++mt) {
            const int mrow = mt * 16 + c;
            ah0[mt] = *(const bf16x8*)&H[mrow][quad * 8];
            ah1[mt] = *(const bf16x8*)&H[mrow][32 + quad * 8];
            ax0[mt] = *(const bf16x8*)&X[mrow][quad * 8];
            ax1[mt] = *(const bf16x8*)&X[mrow][32 + quad * 8];
        }
        if (t < LSEQ - 1) {
            const ushort_t* gp = agg + (s0 + sl) * (LSEQ * HDIM) + (t + 1) * HDIM + k0;
            *(uint4*)xr = *(const uint4*)gp;
        }
        ushort_t hnb[2][4];
#pragma unroll
        for (int mt = 0; mt < 2; ++mt) {
            f32x4 gh[3], gi[3];
#pragma unroll
            for (int g = 0; g < 3; ++g) {
                f32x4 acc = {0.f, 0.f, 0.f, 0.f};
                acc = __builtin_amdgcn_mfma_f32_16x16x32_bf16(ah0[mt], Bh[g][0], acc, 0, 0, 0);
                acc = __builtin_amdgcn_mfma_f32_16x16x32_bf16(ah1[mt], Bh[g][1], acc, 0, 0, 0);
                gh[g] = acc;
                f32x4 acc2 = {0.f, 0.f, 0.f, 0.f};
                acc2 = __builtin_amdgcn_mfma_f32_16x16x32_bf16(ax0[mt], Bi[g][0], acc2, 0, 0, 0);
                acc2 = __builtin_amdgcn_mfma_f32_16x16x32_bf16(ax1[mt], Bi[g][1], acc2, 0, 0, 0);
                gi[g] = acc2;
            }
#pragma unroll
            for (int rg = 0; rg < 4; ++rg) {
                float r = sigm(bi[0] + gi[0][rg] + bh[0] + gh[0][rg]);
                float z = sigm(bi[1] + gi[1][rg] + bh[1] + gh[1][rg]);
                float n = tanh_fast(bi[2] + gi[2][rg] + r * (bh[2] + gh[2][rg]));
                float hv = (1.f - z) * n + z * hold[mt][rg];
                hold[mt][rg] = hv;
                hnb[mt][rg] = fbf(hv);
            }
        }
        __syncthreads();   // B: all reads done
#pragma unroll
        for (int mt = 0; mt < 2; ++mt)
#pragma unroll
            for (int rg = 0; rg < 4; ++rg) {
                const int sloc = mt * 16 + quad * 4 + rg;
                H[sloc][j] = hnb[mt][rg];
            }
    }
#pragma unroll
    for (int mt = 0; mt < 2; ++mt)
#pragma unroll
        for (int rg = 0; rg < 4; ++rg) {
            const int sloc = mt * 16 + quad * 4 + rg;
            h2out[(s0 + sloc) * HDIM + j] = hold[mt][rg];
        }
}

extern "C" void kernel_launch(void* const* d_in, const int* in_sizes, int n_in,
                              void* d_out, int out_size, void* d_ws, size_t ws_size,
                              hipStream_t stream)
{
    const float* data     = (const float*)d_in[0];
    const float* features = (const float*)d_in[1];
    const int*   edges    = (const int*)d_in[2];
    const float* Wih1     = (const float*)d_in[3];
    const float* Whh1     = (const float*)d_in[4];
    const float* bih1     = (const float*)d_in[5];
    const float* bhh1     = (const float*)d_in[6];
    const float* W1       = (const float*)d_in[7];
    const float* b1       = (const float*)d_in[8];
    const float* W2       = (const float*)d_in[9];
    const float* b2       = (const float*)d_in[10];
    const float* W3       = (const float*)d_in[11];
    const float* b3       = (const float*)d_in[12];
    const float* Wih2     = (const float*)d_in[13];
    const float* Whh2     = (const float*)d_in[14];
    const float* bih2     = (const float*)d_in[15];
    const float* bhh2     = (const float*)d_in[16];

    float*    out  = (float*)d_out;
    char*     ws   = (char*)d_ws;
    ushort_t* out1 = (ushort_t*)ws;                    // bf16 intermediate
    ushort_t* agg  = (ushort_t*)(ws + OUT1_BYTES);     // bf16 GAT output
    int*      meta = (int*)(ws + OUT1_BYTES + AGG_BYTES);
    int*   degree   = meta;                       // [2000]
    int*   cursor   = meta + NNODE;               // [2000]
    int*   rowstart = meta + 2 * NNODE;           // [2000]
    int*   srcids   = meta + 3 * NNODE;           // [16000]
    int*   eids     = meta + 3 * NNODE + NEDGE;   // [16000]
    float* alphas   = (float*)(meta + 3 * NNODE + 2 * NEDGE);  // [36000]

    hipMemsetAsync(meta, 0, 2 * NNODE * sizeof(int), stream);   // degree+cursor

    count_kernel<<<(NEDGE + 255) / 256, 256, 0, stream>>>(edges, degree);
    scan_kernel<<<1, 256, 0, stream>>>(degree, rowstart);
    scatter_kernel<<<(NEDGE + 255) / 256, 256, 0, stream>>>(edges, rowstart, cursor,
                                                            srcids, eids);
    alpha_kernel<<<(NEDGE + NNODE) / 4, 256, 0, stream>>>(features, edges,
                                                          W1, b1, W2, b2, alphas);

    gru1_kernel<<<NSEQ / 32, 256, 0, stream>>>(data, Wih1, Whh1, bih1, bhh1, out1, out);
    gat_csr_kernel<<<dim3(NNODE, 3), 256, 0, stream>>>(out1, degree, rowstart, srcids,
                                                       eids, alphas, W3, b3, agg);
    gru2_kernel<<<NSEQ / 32, 256, 0, stream>>>(agg, Wih2, Whh2, bih2, bhh2,
                                               out + NNODE * NB * HDIM);
}